// Round 2
// baseline (390.987 us; speedup 1.0000x reference)
//
#include <hip/hip_runtime.h>
#include <hip/hip_bf16.h>
#include <stdint.h>

#define SEQ   2048
#define BATCH 2
#define DIM   1024
#define NHEAD 16
#define HD    64
#define NT    (BATCH*SEQ)   // 4096 tokens
#define N3    (3*DIM)       // 3072

typedef __attribute__((ext_vector_type(4))) float  f32x4;
typedef __attribute__((ext_vector_type(8))) short  s16x8;
typedef __attribute__((ext_vector_type(4))) unsigned short u16x4;

__device__ __forceinline__ unsigned short f2bf(float x){
  union { float f; uint32_t u; } v; v.f = x;
  return (unsigned short)((v.u + 0x7fffu + ((v.u >> 16) & 1u)) >> 16);
}
__device__ __forceinline__ float bf2f(unsigned short u){
  union { uint32_t u; float f; } v; v.u = ((uint32_t)u) << 16;
  return v.f;
}
__device__ __forceinline__ void gload16(const void* g, void* l){
  __builtin_amdgcn_global_load_lds((const __attribute__((address_space(1))) void*)g,
                                   (__attribute__((address_space(3))) void*)l, 16, 0, 0);
}
#define MFMA(a,b,c) __builtin_amdgcn_mfma_f32_16x16x32_bf16((a),(b),(c),0,0,0)

// ---------------- split fp32 -> bf16 hi/lo ----------------
__global__ __launch_bounds__(256) void k_split(const float* __restrict__ in,
                                               unsigned short* __restrict__ hi,
                                               unsigned short* __restrict__ lo, int n4){
  int i = blockIdx.x*256 + threadIdx.x;
  if (i >= n4) return;
  f32x4 v = ((const f32x4*)in)[i];
  u16x4 h, l;
#pragma unroll
  for (int e=0;e<4;e++){ unsigned short hh = f2bf(v[e]); h[e]=hh; l[e]=f2bf(v[e]-bf2f(hh)); }
  ((u16x4*)hi)[i]=h; ((u16x4*)lo)[i]=l;
}

// ---------------- transpose + split: in[R][C] -> outT[C][R] ----------------
__global__ void k_splitT(const float* __restrict__ in,
                         unsigned short* __restrict__ hiT,
                         unsigned short* __restrict__ loT, int R, int C){
  __shared__ float t[32][33];
  int c0 = blockIdx.x*32, r0 = blockIdx.y*32;
  int tx = threadIdx.x, ty = threadIdx.y;
#pragma unroll
  for (int j=0;j<32;j+=8) t[ty+j][tx] = in[(size_t)(r0+ty+j)*C + c0+tx];
  __syncthreads();
#pragma unroll
  for (int j=0;j<32;j+=8){
    float v = t[tx][ty+j];
    unsigned short hh = f2bf(v);
    size_t o = (size_t)(c0+ty+j)*R + r0+tx;
    hiT[o]=hh; loT[o]=f2bf(v-bf2f(hh));
  }
}

// ---------------- split-bf16 GEMM: C[M,N] = A[M,K] * B^T[N,K] + bias ----------------
// EPI==0: N=3072, epilogue = bias + RoPE, scatter q,k,v [B,H,SEQ,HD] bf16
// EPI==1: N=1024, epilogue = bias, write fp32 out
template<int EPI>
__global__ __launch_bounds__(256) void k_gemm(
    const unsigned short* __restrict__ Ahi, const unsigned short* __restrict__ Alo,
    const unsigned short* __restrict__ Bhi, const unsigned short* __restrict__ Blo,
    const float* __restrict__ bias,
    unsigned short* __restrict__ qb, unsigned short* __restrict__ kbp,
    unsigned short* __restrict__ vbp, float* __restrict__ outp){
  __shared__ unsigned short sA[2][128*32];
  __shared__ unsigned short sB[2][128*32];
  const int tid = threadIdx.x;
  const int w = tid>>6, lane = tid&63;
  const int lr = lane&15, lk = lane>>4;
  const int wm = (w>>1)*64, wn = (w&1)*64;
  const int m0 = blockIdx.y*128, n0 = blockIdx.x*128;

  f32x4 acc[4][4];
#pragma unroll
  for (int m=0;m<4;m++)
#pragma unroll
    for (int n=0;n<4;n++) acc[m][n] = (f32x4){0.f,0.f,0.f,0.f};

  const int srow  = lane>>2;       // row within 16-row chunk
  const int sbyte = (lane&3)*16;   // byte col within 64B row

  for (int kt=0; kt<1024/32; ++kt){
    const int k0 = kt*32;
#pragma unroll
    for (int cc=0; cc<2; ++cc){
      const int chunk = w*2+cc;
      const int row = chunk*16 + srow;
      const size_t aoff = ((size_t)(m0+row)*1024 + k0)*2 + sbyte;
      const size_t boff = ((size_t)(n0+row)*1024 + k0)*2 + sbyte;
      gload16((const char*)Ahi + aoff, (char*)(&sA[0][0]) + chunk*1024);
      gload16((const char*)Alo + aoff, (char*)(&sA[1][0]) + chunk*1024);
      gload16((const char*)Bhi + boff, (char*)(&sB[0][0]) + chunk*1024);
      gload16((const char*)Blo + boff, (char*)(&sB[1][0]) + chunk*1024);
    }
    __syncthreads();

    s16x8 ah[4], al[4], bh[4], bl[4];
#pragma unroll
    for (int m=0;m<4;m++){
      const int off = (wm + m*16 + lr)*64 + lk*16;
      ah[m] = *(const s16x8*)((const char*)(&sA[0][0]) + off);
      al[m] = *(const s16x8*)((const char*)(&sA[1][0]) + off);
    }
#pragma unroll
    for (int n=0;n<4;n++){
      const int off = (wn + n*16 + lr)*64 + lk*16;
      bh[n] = *(const s16x8*)((const char*)(&sB[0][0]) + off);
      bl[n] = *(const s16x8*)((const char*)(&sB[1][0]) + off);
    }
#pragma unroll
    for (int m=0;m<4;m++)
#pragma unroll
      for (int n=0;n<4;n++){
        acc[m][n] = MFMA(ah[m], bh[n], acc[m][n]);
        acc[m][n] = MFMA(ah[m], bl[n], acc[m][n]);
        acc[m][n] = MFMA(al[m], bh[n], acc[m][n]);
      }
    __syncthreads();
  }

  // epilogue
#pragma unroll
  for (int m=0;m<4;m++)
#pragma unroll
    for (int n=0;n<4;n++)
#pragma unroll
      for (int r=0;r<4;r++){
        const int gm = m0 + wm + m*16 + lk*4 + r;
        const int gn = n0 + wn + n*16 + lr;
        float val = acc[m][n][r] + bias[gn];
        if (EPI == 0){
          const int three = gn>>10, rem = gn&1023, h = rem>>6, d = rem&63;
          const int b = gm>>11, t = gm&2047;
          const float partner = __shfl_xor(val, 1);
          const size_t dst = (((size_t)(b*NHEAD + h))*SEQ + t)*HD + d;
          if (three < 2){
            const float fi = (float)(d>>1);
            const float ang = (float)t * exp2f(fi * -0.41524101186f); // -log2(10000)/32
            float sn, cs; sincosf(ang, &sn, &cs);
            float o;
            if (d & 1) o = partner*sn + val*cs;   // im' = re*sin + im*cos
            else       o = val*cs - partner*sn;   // re' = re*cos - im*sin
            ((three==0)? qb : kbp)[dst] = f2bf(o);
          } else {
            vbp[dst] = f2bf(val);
          }
        } else {
          outp[(size_t)gm*DIM + gn] = val;
        }
      }
}

// ---------------- flash attention: per (bh, 64-row q tile) ----------------
__global__ __launch_bounds__(256) void k_attn(const unsigned short* __restrict__ qb,
                                              const unsigned short* __restrict__ kb,
                                              const unsigned short* __restrict__ vb,
                                              unsigned short* __restrict__ aohi,
                                              unsigned short* __restrict__ aolo){
  __shared__ unsigned short vt[64][72];      // V^T tile [hd][kv], padded
  __shared__ unsigned short pl[4][16][72];   // per-wave P tile [q][kv], padded
  const int tid = threadIdx.x, w = tid>>6, lane = tid&63;
  const int lr = lane&15, lk = lane>>4;
  const int bh = blockIdx.y, qt = blockIdx.x;
  const size_t base = (size_t)bh*SEQ*HD;
  const int q0 = qt*64 + w*16;
  const float scale = 0.125f;

  s16x8 qf[2];
  {
    const unsigned short* qs = qb + base + (size_t)(q0+lr)*HD + lk*8;
    qf[0] = *(const s16x8*)qs;
    qf[1] = *(const s16x8*)(qs+32);
  }
  f32x4 oa[4];
#pragma unroll
  for (int cb=0;cb<4;cb++) oa[cb] = (f32x4){0.f,0.f,0.f,0.f};
  float m_r[4] = {-INFINITY,-INFINITY,-INFINITY,-INFINITY};
  float l_r[4] = {0.f,0.f,0.f,0.f};

  for (int kv0=0; kv0<SEQ; kv0+=64){
    { // stage V^T
      const int kvr = tid>>2, hb = (tid&3)*16;
      const unsigned short* vs = vb + base + (size_t)(kv0+kvr)*HD + hb;
      s16x8 v0 = *(const s16x8*)vs, v1 = *(const s16x8*)(vs+8);
#pragma unroll
      for (int e=0;e<8;e++){ vt[hb+e][kvr] = (unsigned short)v0[e]; vt[hb+8+e][kvr] = (unsigned short)v1[e]; }
    }
    __syncthreads();

    float sc[4][4], p[4][4];
#pragma unroll
    for (int c=0;c<4;c++){
      const unsigned short* ks = kb + base + (size_t)(kv0 + c*16 + lr)*HD + lk*8;
      s16x8 kf0 = *(const s16x8*)ks, kf1 = *(const s16x8*)(ks+32);
      f32x4 s = (f32x4){0.f,0.f,0.f,0.f};
      s = MFMA(qf[0], kf0, s);
      s = MFMA(qf[1], kf1, s);
#pragma unroll
      for (int r=0;r<4;r++) sc[c][r] = s[r]*scale;
    }
#pragma unroll
    for (int r=0;r<4;r++){
      float mx = fmaxf(fmaxf(sc[0][r],sc[1][r]), fmaxf(sc[2][r],sc[3][r]));
      mx = fmaxf(mx, __shfl_xor(mx,1)); mx = fmaxf(mx, __shfl_xor(mx,2));
      mx = fmaxf(mx, __shfl_xor(mx,4)); mx = fmaxf(mx, __shfl_xor(mx,8));
      const float mn = fmaxf(m_r[r], mx);
      const float al = __expf(m_r[r]-mn);
      float rs = 0.f;
#pragma unroll
      for (int c=0;c<4;c++){ p[c][r] = __expf(sc[c][r]-mn); rs += p[c][r]; }
      rs += __shfl_xor(rs,1); rs += __shfl_xor(rs,2);
      rs += __shfl_xor(rs,4); rs += __shfl_xor(rs,8);
      l_r[r] = l_r[r]*al + rs;
      m_r[r] = mn;
#pragma unroll
      for (int cb=0;cb<4;cb++) oa[cb][r] *= al;
    }
#pragma unroll
    for (int c=0;c<4;c++)
#pragma unroll
      for (int r=0;r<4;r++) pl[w][lk*4+r][c*16+lr] = f2bf(p[c][r]);

    s16x8 pa0 = *(const s16x8*)&pl[w][lr][lk*8];
    s16x8 pa1 = *(const s16x8*)&pl[w][lr][lk*8+32];
#pragma unroll
    for (int cb=0;cb<4;cb++){
      s16x8 vf0 = *(const s16x8*)&vt[cb*16+lr][lk*8];
      s16x8 vf1 = *(const s16x8*)&vt[cb*16+lr][lk*8+32];
      oa[cb] = MFMA(pa0, vf0, oa[cb]);
      oa[cb] = MFMA(pa1, vf1, oa[cb]);
    }
    __syncthreads();
  }

  const int b = bh>>4, h = bh&15;
#pragma unroll
  for (int r=0;r<4;r++){
    const float inv = 1.0f/l_r[r];
    const int t = q0 + lk*4 + r;
#pragma unroll
    for (int cb=0;cb<4;cb++){
      const float o = oa[cb][r]*inv;
      const size_t dst = ((size_t)(b*SEQ + t))*DIM + h*HD + cb*16 + lr;
      unsigned short hh = f2bf(o);
      aohi[dst] = hh; aolo[dst] = f2bf(o - bf2f(hh));
    }
  }
}

extern "C" void kernel_launch(void* const* d_in, const int* in_sizes, int n_in,
                              void* d_out, int out_size, void* d_ws, size_t ws_size,
                              hipStream_t stream){
  const float* x     = (const float*)d_in[0];
  const float* Wqkv  = (const float*)d_in[1];
  const float* bqkv  = (const float*)d_in[2];
  const float* Wproj = (const float*)d_in[3];
  const float* bproj = (const float*)d_in[4];
  float* out = (float*)d_out;

  char* ws = (char*)d_ws;
  size_t off = 0;
  auto alloc = [&](size_t bytes)->char*{
    char* p = ws + off; off += (bytes + 255) & ~(size_t)255; return p;
  };
  unsigned short* xhi    = (unsigned short*)alloc((size_t)NT*DIM*2);
  unsigned short* xlo    = (unsigned short*)alloc((size_t)NT*DIM*2);
  unsigned short* wqT_hi = (unsigned short*)alloc((size_t)N3*DIM*2);
  unsigned short* wqT_lo = (unsigned short*)alloc((size_t)N3*DIM*2);
  unsigned short* wpT_hi = (unsigned short*)alloc((size_t)DIM*DIM*2);
  unsigned short* wpT_lo = (unsigned short*)alloc((size_t)DIM*DIM*2);
  unsigned short* q_bf   = (unsigned short*)alloc((size_t)NT*DIM*2);
  unsigned short* k_bf   = (unsigned short*)alloc((size_t)NT*DIM*2);
  unsigned short* v_bf   = (unsigned short*)alloc((size_t)NT*DIM*2);
  unsigned short* ao_hi  = (unsigned short*)alloc((size_t)NT*DIM*2);
  unsigned short* ao_lo  = (unsigned short*)alloc((size_t)NT*DIM*2);

  k_split<<<(NT*DIM/4)/256, 256, 0, stream>>>(x, xhi, xlo, NT*DIM/4);
  k_splitT<<<dim3(N3/32, DIM/32), dim3(32,8), 0, stream>>>(Wqkv, wqT_hi, wqT_lo, DIM, N3);
  k_splitT<<<dim3(DIM/32, DIM/32), dim3(32,8), 0, stream>>>(Wproj, wpT_hi, wpT_lo, DIM, DIM);
  k_gemm<0><<<dim3(N3/128, NT/128), 256, 0, stream>>>(xhi, xlo, wqT_hi, wqT_lo, bqkv,
                                                      q_bf, k_bf, v_bf, nullptr);
  k_attn<<<dim3(SEQ/64, BATCH*NHEAD), 256, 0, stream>>>(q_bf, k_bf, v_bf, ao_hi, ao_lo);
  k_gemm<1><<<dim3(DIM/128, NT/128), 256, 0, stream>>>(ao_hi, ao_lo, wpT_hi, wpT_lo, bproj,
                                                       nullptr, nullptr, nullptr, out);
}